// Round 16
// baseline (30616.653 us; speedup 1.0000x reference)
//
#include <hip/hip_runtime.h>
#include <hip/hip_bf16.h>
#include <stdint.h>

typedef uint32_t u32;
typedef uint64_t u64;
typedef __bf16  bf16x8 __attribute__((ext_vector_type(8)));
typedef float   f32x4  __attribute__((ext_vector_type(4)));

#define DEVI __device__ __forceinline__

// ---------------- problem constants ----------------
#define BB    64
#define NN    512
#define BN    32768            // B*N
#define STEPS 119
#define HD    256
#define OSZ   3899392ull       // 64*119*512

// ---------------- geometry: 4 waves/WG x 4 jc, WG owns 64 rows (4 M-tiles); 2 WGs/CU ----------------
#define NWAVE   4
#define MT      4
#define WGROWS  64
#define NWG     512
#define NTHR    256

// ---------------- packed weight stream (bf16) ----------------
#define L0_STAGE_BYTES  36864
#define L1A_STAGE_BYTES 32768
#define L1B_STAGE_BYTES 36864
#define HEAD_STAGE_BYTES 9216
#define L0_OFF      0u
#define L1_OFF      (16u*L0_STAGE_BYTES)                 // 589824
#define L1_JC_BYTES (L1A_STAGE_BYTES + L1B_STAGE_BYTES)  // 69632
#define HEAD_OFF    (L1_OFF + 16u*L1_JC_BYTES)           // 1703936
#define PACKED_BYTES (HEAD_OFF + HEAD_STAGE_BYTES)       // 1713152

// ws layout (bytes)
#define PREP_OFF  1835008u                  // A[1024], bias0[1024] f32
#define EPS_OFF   4194304u                  // 119*32768 f32

// LDS: SINGLE h buffers [64][256] bf16 (32KB each) + 4KB aug => 68KB => 2 WGs/CU
#define H0B   0u
#define H1B   32768u
#define AUG_OFF 65536u                      // [64 rows][32 bf16]; cols 8..31 stay zero
#define SMEM_TOTAL 69632u

// ---------------- math helpers ----------------
DEVI float exp2g(float x){ return __builtin_amdgcn_exp2f(x); }
DEVI float rcpg (float x){ return __builtin_amdgcn_rcpf(x); }
DEVI float log2g(float x){ return __builtin_amdgcn_logf(x); }
#define LOG2E 1.4426950408889634f
#define LN2   0.6931471805599453f
DEVI float sigm(float x){ return rcpg(1.0f + exp2g(-LOG2E*x)); }
DEVI float tanh_(float x){
  float ax = fabsf(x);
  float e  = exp2g(2.0f*LOG2E*ax);
  float r  = 1.0f - 2.0f*rcpg(e + 1.0f);
  return copysignf(r, x);
}
DEVI float softplus_(float x){
  float ax = fabsf(x);
  return fmaxf(x, 0.0f) + log2g(1.0f + exp2g(-LOG2E*ax)) * LN2;
}
DEVI u32 f2bf(float f){ u32 u = __float_as_uint(f); return (u + 0x7FFFu + ((u>>16)&1u)) >> 16; }

DEVI f32x4 mfma16(bf16x8 a, bf16x8 b, f32x4 c){
  return __builtin_amdgcn_mfma_f32_16x16x32_bf16(a, b, c, 0, 0, 0);
}
DEVI bf16x8 bzero8(){ bf16x8 z;
#pragma unroll
  for (int i=0;i<8;++i) z[i] = (__bf16)0.0f;
  return z; }
DEVI bf16x8 relu8(bf16x8 v){ bf16x8 r;
#pragma unroll
  for (int i=0;i<8;++i){ float x = (float)v[i]; r[i] = x > 0.0f ? v[i] : (__bf16)0.0f; }
  return r; }

// ---------------- prep: A[] and folded bias for layer0 (verified r2) ----------------
__global__ void k_dots(const float* __restrict__ W_embed, const float* __restrict__ b_embed,
                       const float* __restrict__ W_ih0, const float* __restrict__ b_ih0,
                       const float* __restrict__ b_hh0, float* __restrict__ prep)
{
  int i = blockIdx.x*256 + threadIdx.x;
  if (i >= 1024) return;
  float a = 0.f, bb = 0.f;
  for (int e = 0; e < 64; ++e){
    float w = W_ih0[i*67 + e];
    a  += W_embed[e] * w;
    bb += b_embed[e] * w;
  }
  prep[i]        = a;
  prep[1024 + i] = bb + b_ih0[i] + b_hh0[i];
}

// ---------------- prep: pack all weights into stream order (bf16, verified r3) ----------------
__global__ void k_pack(const float* __restrict__ W_ih0, const float* __restrict__ W_hh0,
                       const float* __restrict__ W_ih1, const float* __restrict__ W_hh1,
                       const float* __restrict__ W_mu,  const float* __restrict__ b_mu,
                       const float* __restrict__ W_sig, const float* __restrict__ b_sig,
                       const float* __restrict__ b_ih1, const float* __restrict__ b_hh1,
                       const float* __restrict__ prep, uint8_t* __restrict__ ws)
{
  u32 e = blockIdx.x*256 + threadIdx.x;
  if (e >= PACKED_BYTES/2) return;
  u32 byte = e*2;
  float v = 0.0f;
  if (byte < L1_OFF){
    u32 jc  = byte / L0_STAGE_BYTES;
    u32 rr  = byte % L0_STAGE_BYTES;
    u32 f16i = rr >> 4;  u32 j = (rr & 15) >> 1;
    u32 lane = f16i & 63; u32 kkg = f16i >> 6;
    u32 kk = kkg >> 2, g = kkg & 3;
    u32 row = g*256 + jc*16 + (lane & 15);
    u32 k   = kk*32 + (lane>>4)*8 + j;
    if (k < 256) v = W_hh0[row*256 + k];
    else { u32 ka = k - 256;
      v = (ka==0) ? prep[row]
        : (ka<=3) ? W_ih0[row*67 + 64 + (ka-1)]
        : (ka==4) ? prep[1024 + row] : 0.0f; }
  } else if (byte < HEAD_OFF){
    u32 rel = byte - L1_OFF;
    u32 jc  = rel / L1_JC_BYTES;
    u32 r2  = rel % L1_JC_BYTES;
    u32 kh  = (r2 >= L1A_STAGE_BYTES) ? 1u : 0u;
    u32 r3  = r2 - kh*L1A_STAGE_BYTES;
    u32 f16i = r3 >> 4;  u32 j = (r3 & 15) >> 1;
    u32 lane = f16i & 63; u32 kkg = f16i >> 6;
    u32 kk = (kkg >> 2) + kh*8; u32 g = kkg & 3;
    u32 row = g*256 + jc*16 + (lane & 15);
    u32 k   = kk*32 + (lane>>4)*8 + j;
    if (k < 256)       v = W_ih1[row*256 + k];
    else if (k < 512)  v = W_hh1[row*256 + (k-256)];
    else { u32 ka = k - 512; v = (ka==4) ? (b_ih1[row] + b_hh1[row]) : 0.0f; }
  } else {
    u32 rel = byte - HEAD_OFF;
    u32 f16i = rel >> 4; u32 j = (rel & 15) >> 1;
    u32 lane = f16i & 63; u32 kk = f16i >> 6;
    u32 hrow = lane & 15;
    u32 k = kk*32 + (lane>>4)*8 + j;
    if (hrow == 0)      v = (k < 256) ? W_mu[k]  : (k==260 ? b_mu[0]  : 0.0f);
    else if (hrow == 1) v = (k < 256) ? W_sig[k] : (k==260 ? b_sig[0] : 0.0f);
    else v = 0.0f;
  }
  ((uint16_t*)ws)[e] = (uint16_t)f2bf(v);
}

// ---------------- eps (VERIFIED round 2): partitionable threefry, out = x0^x1 ----------------
DEVI float erfinv_f(float x){
  float w = -log1pf(-x*x);
  float p;
  if (w < 5.0f){
    w = w - 2.5f;
    p = 2.81022636e-08f;
    p = fmaf(p, w, 3.43273939e-07f);
    p = fmaf(p, w, -3.5233877e-06f);
    p = fmaf(p, w, -4.39150654e-06f);
    p = fmaf(p, w, 0.00021858087f);
    p = fmaf(p, w, -0.00125372503f);
    p = fmaf(p, w, -0.00417768164f);
    p = fmaf(p, w, 0.246640727f);
    p = fmaf(p, w, 1.50140941f);
  } else {
    w = sqrtf(w) - 3.0f;
    p = -0.000200214257f;
    p = fmaf(p, w, 0.000100950558f);
    p = fmaf(p, w, 0.00134934322f);
    p = fmaf(p, w, -0.00367342844f);
    p = fmaf(p, w, 0.00573950773f);
    p = fmaf(p, w, -0.0076224613f);
    p = fmaf(p, w, 0.00943887047f);
    p = fmaf(p, w, 1.00167406f);
    p = fmaf(p, w, 2.83297682f);
  }
  return p*x;
}
__global__ void k_eps(float* __restrict__ epsbuf){
  u32 i = blockIdx.x*256u + threadIdx.x;
  if (i >= (u32)(STEPS*BN)) return;
  const u32 ks0 = 0u, ks1 = 42u, ks2 = 0x1BD11BF0u;  // 0x1BD11BDA ^ 0 ^ 42
  u32 x0 = 0u + ks0, x1 = i + ks1;
#define TFR(r) { x0 += x1; x1 = (x1<<r)|(x1>>(32-r)); x1 ^= x0; }
  TFR(13) TFR(15) TFR(26) TFR(6)   x0 += ks1; x1 += ks2 + 1u;
  TFR(17) TFR(29) TFR(16) TFR(24)  x0 += ks2; x1 += ks0 + 2u;
  TFR(13) TFR(15) TFR(26) TFR(6)   x0 += ks0; x1 += ks1 + 3u;
  TFR(17) TFR(29) TFR(16) TFR(24)  x0 += ks1; x1 += ks2 + 4u;
  TFR(13) TFR(15) TFR(26) TFR(6)   x0 += ks2; x1 += ks0 + 5u;
#undef TFR
  u32 bits = x0 ^ x1;
  float f = __uint_as_float((bits >> 9) | 0x3F800000u) - 1.0f;
  const float lo = -0.99999994f;
  float u = fmaf(f, 2.0f, lo);
  u = fmaxf(u, lo);
  epsbuf[i] = 1.41421354f * erfinv_f(u);
}

// ---------------- reals output (verified r2) ----------------
__global__ void k_reals(const float* __restrict__ hist, const float* __restrict__ fut,
                        float* __restrict__ out)
{
  u32 i = blockIdx.x*256 + threadIdx.x;
  if (i >= (u32)OSZ) return;
  u32 n = i & 511; u32 rest = i >> 9;
  u32 t = rest % STEPS; u32 b = rest / STEPS;
  u32 tt = t + 1;
  float v = (tt < 96) ? hist[(((u64)b*96 + tt)*512 + n)*4]
                      : fut [(((u64)b*24 + (tt-96))*512 + n)*4];
  out[OSZ + i] = v;
}

// ---------------- main: 4-wave N-split, single h buffers + reg-hold, 2 WGs/CU ----------------
__global__ __launch_bounds__(NTHR, 1) void k_main(
    const float* __restrict__ hist, const float* __restrict__ fut,
    const uint8_t* __restrict__ wpack, const float* __restrict__ eps,
    float* __restrict__ out)
{
  __shared__ uint8_t smem[SMEM_TOTAL];
  const int tid = threadIdx.x, lane = tid & 63, wid = tid >> 6;
  const int cl = lane & 15, kg = lane >> 4;
  const int m0w = blockIdx.x*WGROWS;          // WG-wide row base

  // B-fragment direct load (shared by all 4 M-tiles)
#define BFR(BASE, BLK) (*(const bf16x8*)(wpack + (BASE) + (((u32)(BLK)*64u + (u32)lane)*16u)))
  // A-fragment read from an h-buffer (r3-verified layout + swizzle); row = MTI*16+cl
#define AFRAG(REG, MTI, KK) (*(const bf16x8*)(smem + (REG) + \
    ((((u32)((MTI)*16 + cl))*512u + (u32)(KK)*64u + (u32)kg*16u) ^ (((u32)((MTI)*16 + cl) & 7u) << 4))))
  // aug A-fragment read: [64 rows][32 bf16]; kg=0 -> cols0..7 (real), kg>0 -> zeros
#define AUGR(MTI) (*(const bf16x8*)(smem + AUG_OFF + ((u32)((MTI)*16 + cl))*64u + (u32)kg*16u))
  // pointwise h store offset; row, unit col = JC*16+cl
#define HOFF(REG, ROW, JC) ((REG) + ((((u32)(ROW))*512u + (u32)((JC)*16+cl)*2u) ^ ((((u32)(ROW)) & 7u) << 4)))

  // persistent per-thread state: c packed bf16 mt-pairs (wave's own 4 jc) = 64 regs
  u32 c0p[4][4][2];   // [j][r][pk] ; pk0 = mt0/1, pk1 = mt2/3
  u32 c1p[4][4][2];
#pragma unroll
  for (int j=0;j<4;++j)
#pragma unroll
    for (int r=0;r<4;++r){ c0p[j][r][0]=0u; c0p[j][r][1]=0u; c1p[j][r][0]=0u; c1p[j][r][1]=0u; }

  // zero H0, H1 (h=0 at t=0) and AUG (cols 8..31 stay 0 forever)
  {
    bf16x8 z = bzero8();
#pragma unroll
    for (int i = 0; i < 8; ++i){
      u32 off = ((u32)tid + (u32)i*NTHR)*16u;
      *(bf16x8*)(smem + H0B + off) = z;
      *(bf16x8*)(smem + H1B + off) = z;
    }
    *(bf16x8*)(smem + AUG_OFF + (u32)tid*16u) = z;
  }
  __syncthreads();

  u32 hold[4][4][2];   // packed h_new staging (transient per phase)

#pragma unroll 1
  for (int t = 0; t < STEPS; ++t){
    // -------- phase A: wave 0 writes this step's aug rows --------
    if (wid == 0 && kg == 0){
#pragma unroll
      for (int mt=0; mt<MT; ++mt){
        u32 mg = (u32)m0w + mt*16 + cl, b = mg >> 9, n = mg & 511;
        float4 dt  = (t   < 96) ? ((const float4*)hist)[(u64)(b*96 + t)*512 + n]
                                : ((const float4*)fut )[(u64)(b*24 + (t-96))*512 + n];
        int t1 = t + 1;
        float4 dt1 = (t1  < 96) ? ((const float4*)hist)[(u64)(b*96 + t1)*512 + n]
                                : ((const float4*)fut )[(u64)(b*24 + (t1-96))*512 + n];
        bf16x8 a = bzero8();
        a[0] = (__bf16)dt.x; a[1] = (__bf16)dt1.y; a[2] = (__bf16)dt1.z; a[3] = (__bf16)dt1.w;
        a[4] = (__bf16)1.0f;
        *(bf16x8*)(smem + AUG_OFF + ((u32)(mt*16 + cl))*64u) = a;
      }
    }
    __syncthreads();   // aug(t) visible; prior-step head reads of H1 done

    // ===================== LAYER 0 compute (reads H0 = h0_old) =====================
#pragma unroll 1
    for (int j = 0; j < 4; ++j){
      const int jc = wid*4 + j;
      const u32 base = L0_OFF + (u32)jc*L0_STAGE_BYTES;
      f32x4 ac[MT][4];
#pragma unroll
      for (int mt=0; mt<MT; ++mt)
#pragma unroll
        for (int g=0; g<4; ++g) ac[mt][g] = (f32x4){0.f,0.f,0.f,0.f};
#pragma unroll
      for (int kk = 0; kk < 9; ++kk){
        bf16x8 a[MT];
#pragma unroll
        for (int mt=0; mt<MT; ++mt) a[mt] = (kk < 8) ? AFRAG(H0B, mt, kk) : AUGR(mt);
#pragma unroll
        for (int g = 0; g < 4; ++g){
          bf16x8 bfr = BFR(base, kk*4+g);
#pragma unroll
          for (int mt=0; mt<MT; ++mt) ac[mt][g] = mfma16(a[mt], bfr, ac[mt][g]);
        }
      }
#pragma unroll
      for (int r = 0; r < 4; ++r)
#pragma unroll
        for (int pk = 0; pk < 2; ++pk){
          u32 packed = c0p[j][r][pk], newpack = 0u, hpack = 0u;
#pragma unroll
          for (int h = 0; h < 2; ++h){
            int mt = pk*2 + h;
            float iv = sigm (ac[mt][0][r]);
            float fv = sigm (ac[mt][1][r]);
            float gv = tanh_(ac[mt][2][r]);
            float ov = sigm (ac[mt][3][r]);
            float cold = __uint_as_float((h ? (packed >> 16) : (packed & 0xffffu)) << 16);
            float cn = fv*cold + iv*gv;
            newpack |= f2bf(cn) << (h*16);
            float hn = ov*tanh_(cn);
            hpack |= f2bf(hn) << (h*16);
          }
          c0p[j][r][pk] = newpack;
          hold[j][r][pk] = hpack;
        }
    }
    __syncthreads();   // all reads of h0_old complete

    // write h0_new over H0
#pragma unroll
    for (int j = 0; j < 4; ++j){
      const int jc = wid*4 + j;
#pragma unroll
      for (int r = 0; r < 4; ++r)
#pragma unroll
        for (int pk = 0; pk < 2; ++pk)
#pragma unroll
          for (int h = 0; h < 2; ++h){
            int mt = pk*2 + h;
            int row = mt*16 + kg*4 + r;
            *(uint16_t*)(smem + HOFF(H0B, row, jc)) =
                (uint16_t)((hold[j][r][pk] >> (h*16)) & 0xffffu);
          }
    }
    __syncthreads();   // h0_new visible

    // ===================== LAYER 1 compute (stage A: H0=h0_new; stage B: H1=h1_old) =====
#pragma unroll 1
    for (int j = 0; j < 4; ++j){
      const int jc = wid*4 + j;
      const u32 baseA = L1_OFF + (u32)jc*L1_JC_BYTES;
      const u32 baseB = baseA + L1A_STAGE_BYTES;
      f32x4 ac[MT][4];
#pragma unroll
      for (int mt=0; mt<MT; ++mt)
#pragma unroll
        for (int g=0; g<4; ++g) ac[mt][g] = (f32x4){0.f,0.f,0.f,0.f};
#pragma unroll
      for (int kk = 0; kk < 8; ++kk){
        bf16x8 a[MT];
#pragma unroll
        for (int mt=0; mt<MT; ++mt) a[mt] = AFRAG(H0B, mt, kk);
#pragma unroll
        for (int g = 0; g < 4; ++g){
          bf16x8 bfr = BFR(baseA, kk*4+g);
#pragma unroll
          for (int mt=0; mt<MT; ++mt) ac[mt][g] = mfma16(a[mt], bfr, ac[mt][g]);
        }
      }
#pragma unroll
      for (int kk = 0; kk < 9; ++kk){
        bf16x8 a[MT];
#pragma unroll
        for (int mt=0; mt<MT; ++mt) a[mt] = (kk < 8) ? AFRAG(H1B, mt, kk) : AUGR(mt);
#pragma unroll
        for (int g = 0; g < 4; ++g){
          bf16x8 bfr = BFR(baseB, kk*4+g);
#pragma unroll
          for (int mt=0; mt<MT; ++mt) ac[mt][g] = mfma16(a[mt], bfr, ac[mt][g]);
        }
      }
#pragma unroll
      for (int r = 0; r < 4; ++r)
#pragma unroll
        for (int pk = 0; pk < 2; ++pk){
          u32 packed = c1p[j][r][pk], newpack = 0u, hpack = 0u;
#pragma unroll
          for (int h = 0; h < 2; ++h){
            int mt = pk*2 + h;
            float iv = sigm (ac[mt][0][r]);
            float fv = sigm (ac[mt][1][r]);
            float gv = tanh_(ac[mt][2][r]);
            float ov = sigm (ac[mt][3][r]);
            float cold = __uint_as_float((h ? (packed >> 16) : (packed & 0xffffu)) << 16);
            float cn = fv*cold + iv*gv;
            newpack |= f2bf(cn) << (h*16);
            float hn = ov*tanh_(cn);
            hpack |= f2bf(hn) << (h*16);
          }
          c1p[j][r][pk] = newpack;
          hold[j][r][pk] = hpack;
        }
    }
    __syncthreads();   // all reads of h1_old complete

    // write h1_new over H1
#pragma unroll
    for (int j = 0; j < 4; ++j){
      const int jc = wid*4 + j;
#pragma unroll
      for (int r = 0; r < 4; ++r)
#pragma unroll
        for (int pk = 0; pk < 2; ++pk)
#pragma unroll
          for (int h = 0; h < 2; ++h){
            int mt = pk*2 + h;
            int row = mt*16 + kg*4 + r;
            *(uint16_t*)(smem + HOFF(H1B, row, jc)) =
                (uint16_t)((hold[j][r][pk] >> (h*16)) & 0xffffu);
          }
    }
    __syncthreads();   // h1_new visible

    // ===================== HEAD (wave 0 only; A = relu(h1_new), aug) =====================
    if (wid == 0){
      f32x4 ha[MT];
#pragma unroll
      for (int mt=0; mt<MT; ++mt) ha[mt] = (f32x4){0.f,0.f,0.f,0.f};
#pragma unroll
      for (int kk = 0; kk < 9; ++kk){
        bf16x8 bfr = BFR(HEAD_OFF, kk);
#pragma unroll
        for (int mt=0; mt<MT; ++mt){
          bf16x8 a = (kk < 8) ? relu8(AFRAG(H1B, mt, kk)) : AUGR(mt);
          ha[mt] = mfma16(a, bfr, ha[mt]);
        }
      }
#pragma unroll
      for (int mt = 0; mt < MT; ++mt)
#pragma unroll
        for (int r = 0; r < 4; ++r){
          float a  = ha[mt][r];
          float sp = softplus_(a) + 1e-6f;
          float spn = __shfl_xor(sp, 1, 64);
          u32 mg = (u32)m0w + mt*16 + (u32)(kg*4 + r);
          u64 oidx = (u64)(mg >> 9)*(STEPS*512) + (u64)t*512 + (mg & 511);
          if (cl == 0){
            float e = eps[(u64)t*BN + mg];
            out[oidx]            = fmaf(spn, e, a);   // preds
            out[2ull*OSZ + oidx] = a;                 // mus
          } else if (cl == 1){
            out[3ull*OSZ + oidx] = sp;                // sigmas
          }
        }
    }
    // head's H1 reads are ordered against the next H1 write by barriers A,B,C,D of t+1.
  }
#undef BFR
#undef AFRAG
#undef AUGR
#undef HOFF
}

// ---------------- launch ----------------
extern "C" void kernel_launch(void* const* d_in, const int* in_sizes, int n_in,
                              void* d_out, int out_size, void* d_ws, size_t ws_size,
                              hipStream_t stream)
{
  (void)in_sizes; (void)n_in; (void)out_size; (void)ws_size;
  const float* hist   = (const float*)d_in[0];
  const float* fut    = (const float*)d_in[1];
  const float* W_embed= (const float*)d_in[3];
  const float* b_embed= (const float*)d_in[4];
  const float* W_ih0  = (const float*)d_in[5];
  const float* W_hh0  = (const float*)d_in[6];
  const float* b_ih0  = (const float*)d_in[7];
  const float* b_hh0  = (const float*)d_in[8];
  const float* W_ih1  = (const float*)d_in[9];
  const float* W_hh1  = (const float*)d_in[10];
  const float* b_ih1  = (const float*)d_in[11];
  const float* b_hh1  = (const float*)d_in[12];
  const float* W_mu   = (const float*)d_in[13];
  const float* b_mu   = (const float*)d_in[14];
  const float* W_sig  = (const float*)d_in[15];
  const float* b_sig  = (const float*)d_in[16];
  uint8_t* ws  = (uint8_t*)d_ws;
  float*   out = (float*)d_out;

  hipLaunchKernelGGL(k_dots, dim3(4), dim3(256), 0, stream,
                     W_embed, b_embed, W_ih0, b_ih0, b_hh0, (float*)(ws + PREP_OFF));
  hipLaunchKernelGGL(k_pack, dim3(PACKED_BYTES/2/256), dim3(256), 0, stream,
                     W_ih0, W_hh0, W_ih1, W_hh1, W_mu, b_mu, W_sig, b_sig,
                     b_ih1, b_hh1, (const float*)(ws + PREP_OFF), ws);
  hipLaunchKernelGGL(k_eps, dim3((STEPS*BN)/256), dim3(256), 0, stream,
                     (float*)(ws + EPS_OFF));
  hipLaunchKernelGGL(k_reals, dim3((u32)((OSZ + 255)/256)), dim3(256), 0, stream,
                     hist, fut, out);
  hipLaunchKernelGGL(k_main, dim3(NWG), dim3(NTHR), 0, stream,
                     hist, fut, ws, (const float*)(ws + EPS_OFF), out);
}

// Round 17
// 9245.502 us; speedup vs baseline: 3.3115x; 3.3115x over previous
//
#include <hip/hip_runtime.h>
#include <hip/hip_bf16.h>
#include <stdint.h>

typedef uint32_t u32;
typedef uint64_t u64;
typedef __bf16  bf16x8 __attribute__((ext_vector_type(8)));
typedef float   f32x4  __attribute__((ext_vector_type(4)));

#define DEVI __device__ __forceinline__

// ---------------- problem constants ----------------
#define BB    64
#define NN    512
#define BN    32768            // B*N
#define STEPS 119
#define HD    256
#define OSZ   3899392ull       // 64*119*512

// ---------------- geometry: 4 waves/WG x 4 jc, WG owns 32 rows (2 M-tiles); 2 WGs/CU ----------------
#define NWAVE   4
#define MT      2
#define WGROWS  32
#define NWG     1024
#define NTHR    256

// ---------------- packed weight stream (bf16) ----------------
#define L0_STAGE_BYTES  36864
#define L1A_STAGE_BYTES 32768
#define L1B_STAGE_BYTES 36864
#define HEAD_STAGE_BYTES 9216
#define L0_OFF      0u
#define L1_OFF      (16u*L0_STAGE_BYTES)                 // 589824
#define L1_JC_BYTES (L1A_STAGE_BYTES + L1B_STAGE_BYTES)  // 69632
#define HEAD_OFF    (L1_OFF + 16u*L1_JC_BYTES)           // 1703936
#define PACKED_BYTES (HEAD_OFF + HEAD_STAGE_BYTES)       // 1713152

// ws layout (bytes)
#define PREP_OFF  1835008u                  // A[1024], bias0[1024] f32
#define EPS_OFF   4194304u                  // 119*32768 f32

// LDS: 4 WG-shared h buffers [32 rows][256 units] bf16 = 16KB each (h0 x2, h1 x2)
#define HBUF_SZ   16384u
#define H0_OFF(p) ((u32)(p)*HBUF_SZ)
#define H1_OFF(p) ((2u+(u32)(p))*HBUF_SZ)
#define SMEM_TOTAL (4u*HBUF_SZ)             // 65536 (64KB) -> 2 WGs/CU, 8 waves = 2/SIMD

// ---------------- math helpers ----------------
DEVI float exp2g(float x){ return __builtin_amdgcn_exp2f(x); }
DEVI float rcpg (float x){ return __builtin_amdgcn_rcpf(x); }
DEVI float log2g(float x){ return __builtin_amdgcn_logf(x); }
#define LOG2E 1.4426950408889634f
#define LN2   0.6931471805599453f
DEVI float sigm(float x){ return rcpg(1.0f + exp2g(-LOG2E*x)); }
DEVI float tanh_(float x){
  float ax = fabsf(x);
  float e  = exp2g(2.0f*LOG2E*ax);
  float r  = 1.0f - 2.0f*rcpg(e + 1.0f);
  return copysignf(r, x);
}
DEVI float softplus_(float x){
  float ax = fabsf(x);
  return fmaxf(x, 0.0f) + log2g(1.0f + exp2g(-LOG2E*ax)) * LN2;
}
DEVI u32 f2bf(float f){ u32 u = __float_as_uint(f); return (u + 0x7FFFu + ((u>>16)&1u)) >> 16; }

DEVI f32x4 mfma16(bf16x8 a, bf16x8 b, f32x4 c){
  return __builtin_amdgcn_mfma_f32_16x16x32_bf16(a, b, c, 0, 0, 0);
}
DEVI bf16x8 bzero8(){ bf16x8 z;
#pragma unroll
  for (int i=0;i<8;++i) z[i] = (__bf16)0.0f;
  return z; }
DEVI bf16x8 relu8(bf16x8 v){ bf16x8 r;
#pragma unroll
  for (int i=0;i<8;++i){ float x = (float)v[i]; r[i] = x > 0.0f ? v[i] : (__bf16)0.0f; }
  return r; }

// ---------------- prep: A[] and folded bias for layer0 (verified r2) ----------------
__global__ void k_dots(const float* __restrict__ W_embed, const float* __restrict__ b_embed,
                       const float* __restrict__ W_ih0, const float* __restrict__ b_ih0,
                       const float* __restrict__ b_hh0, float* __restrict__ prep)
{
  int i = blockIdx.x*256 + threadIdx.x;
  if (i >= 1024) return;
  float a = 0.f, bb = 0.f;
  for (int e = 0; e < 64; ++e){
    float w = W_ih0[i*67 + e];
    a  += W_embed[e] * w;
    bb += b_embed[e] * w;
  }
  prep[i]        = a;
  prep[1024 + i] = bb + b_ih0[i] + b_hh0[i];
}

// ---------------- prep: pack all weights into stream order (bf16, verified r3) ----------------
__global__ void k_pack(const float* __restrict__ W_ih0, const float* __restrict__ W_hh0,
                       const float* __restrict__ W_ih1, const float* __restrict__ W_hh1,
                       const float* __restrict__ W_mu,  const float* __restrict__ b_mu,
                       const float* __restrict__ W_sig, const float* __restrict__ b_sig,
                       const float* __restrict__ b_ih1, const float* __restrict__ b_hh1,
                       const float* __restrict__ prep, uint8_t* __restrict__ ws)
{
  u32 e = blockIdx.x*256 + threadIdx.x;
  if (e >= PACKED_BYTES/2) return;
  u32 byte = e*2;
  float v = 0.0f;
  if (byte < L1_OFF){
    u32 jc  = byte / L0_STAGE_BYTES;
    u32 rr  = byte % L0_STAGE_BYTES;
    u32 f16i = rr >> 4;  u32 j = (rr & 15) >> 1;
    u32 lane = f16i & 63; u32 kkg = f16i >> 6;
    u32 kk = kkg >> 2, g = kkg & 3;
    u32 row = g*256 + jc*16 + (lane & 15);
    u32 k   = kk*32 + (lane>>4)*8 + j;
    if (k < 256) v = W_hh0[row*256 + k];
    else { u32 ka = k - 256;
      v = (ka==0) ? prep[row]
        : (ka<=3) ? W_ih0[row*67 + 64 + (ka-1)]
        : (ka==4) ? prep[1024 + row] : 0.0f; }
  } else if (byte < HEAD_OFF){
    u32 rel = byte - L1_OFF;
    u32 jc  = rel / L1_JC_BYTES;
    u32 r2  = rel % L1_JC_BYTES;
    u32 kh  = (r2 >= L1A_STAGE_BYTES) ? 1u : 0u;
    u32 r3  = r2 - kh*L1A_STAGE_BYTES;
    u32 f16i = r3 >> 4;  u32 j = (r3 & 15) >> 1;
    u32 lane = f16i & 63; u32 kkg = f16i >> 6;
    u32 kk = (kkg >> 2) + kh*8; u32 g = kkg & 3;
    u32 row = g*256 + jc*16 + (lane & 15);
    u32 k   = kk*32 + (lane>>4)*8 + j;
    if (k < 256)       v = W_ih1[row*256 + k];
    else if (k < 512)  v = W_hh1[row*256 + (k-256)];
    else { u32 ka = k - 512; v = (ka==4) ? (b_ih1[row] + b_hh1[row]) : 0.0f; }
  } else {
    u32 rel = byte - HEAD_OFF;
    u32 f16i = rel >> 4; u32 j = (rel & 15) >> 1;
    u32 lane = f16i & 63; u32 kk = f16i >> 6;
    u32 hrow = lane & 15;
    u32 k = kk*32 + (lane>>4)*8 + j;
    if (hrow == 0)      v = (k < 256) ? W_mu[k]  : (k==260 ? b_mu[0]  : 0.0f);
    else if (hrow == 1) v = (k < 256) ? W_sig[k] : (k==260 ? b_sig[0] : 0.0f);
    else v = 0.0f;
  }
  ((uint16_t*)ws)[e] = (uint16_t)f2bf(v);
}

// ---------------- eps (VERIFIED round 2): partitionable threefry, out = x0^x1 ----------------
DEVI float erfinv_f(float x){
  float w = -log1pf(-x*x);
  float p;
  if (w < 5.0f){
    w = w - 2.5f;
    p = 2.81022636e-08f;
    p = fmaf(p, w, 3.43273939e-07f);
    p = fmaf(p, w, -3.5233877e-06f);
    p = fmaf(p, w, -4.39150654e-06f);
    p = fmaf(p, w, 0.00021858087f);
    p = fmaf(p, w, -0.00125372503f);
    p = fmaf(p, w, -0.00417768164f);
    p = fmaf(p, w, 0.246640727f);
    p = fmaf(p, w, 1.50140941f);
  } else {
    w = sqrtf(w) - 3.0f;
    p = -0.000200214257f;
    p = fmaf(p, w, 0.000100950558f);
    p = fmaf(p, w, 0.00134934322f);
    p = fmaf(p, w, -0.00367342844f);
    p = fmaf(p, w, 0.00573950773f);
    p = fmaf(p, w, -0.0076224613f);
    p = fmaf(p, w, 0.00943887047f);
    p = fmaf(p, w, 1.00167406f);
    p = fmaf(p, w, 2.83297682f);
  }
  return p*x;
}
__global__ void k_eps(float* __restrict__ epsbuf){
  u32 i = blockIdx.x*256u + threadIdx.x;
  if (i >= (u32)(STEPS*BN)) return;
  const u32 ks0 = 0u, ks1 = 42u, ks2 = 0x1BD11BF0u;  // 0x1BD11BDA ^ 0 ^ 42
  u32 x0 = 0u + ks0, x1 = i + ks1;
#define TFR(r) { x0 += x1; x1 = (x1<<r)|(x1>>(32-r)); x1 ^= x0; }
  TFR(13) TFR(15) TFR(26) TFR(6)   x0 += ks1; x1 += ks2 + 1u;
  TFR(17) TFR(29) TFR(16) TFR(24)  x0 += ks2; x1 += ks0 + 2u;
  TFR(13) TFR(15) TFR(26) TFR(6)   x0 += ks0; x1 += ks1 + 3u;
  TFR(17) TFR(29) TFR(16) TFR(24)  x0 += ks1; x1 += ks2 + 4u;
  TFR(13) TFR(15) TFR(26) TFR(6)   x0 += ks2; x1 += ks0 + 5u;
#undef TFR
  u32 bits = x0 ^ x1;
  float f = __uint_as_float((bits >> 9) | 0x3F800000u) - 1.0f;
  const float lo = -0.99999994f;
  float u = fmaf(f, 2.0f, lo);
  u = fmaxf(u, lo);
  epsbuf[i] = 1.41421354f * erfinv_f(u);
}

// ---------------- reals output (verified r2) ----------------
__global__ void k_reals(const float* __restrict__ hist, const float* __restrict__ fut,
                        float* __restrict__ out)
{
  u32 i = blockIdx.x*256 + threadIdx.x;
  if (i >= (u32)OSZ) return;
  u32 n = i & 511; u32 rest = i >> 9;
  u32 t = rest % STEPS; u32 b = rest / STEPS;
  u32 tt = t + 1;
  float v = (tt < 96) ? hist[(((u64)b*96 + tt)*512 + n)*4]
                      : fut [(((u64)b*24 + (tt-96))*512 + n)*4];
  out[OSZ + i] = v;
}

// ---------------- main: N-split waves, direct-from-L2 weights, 2 WGs/CU ----------------
__global__ __launch_bounds__(NTHR, 1) void k_main(
    const float* __restrict__ hist, const float* __restrict__ fut,
    const uint8_t* __restrict__ wpack, const float* __restrict__ eps,
    float* __restrict__ out)
{
  __shared__ uint8_t smem[SMEM_TOTAL];
  const int tid = threadIdx.x, lane = tid & 63, wid = tid >> 6;
  const int cl = lane & 15, kg = lane >> 4;
  const int m0w = blockIdx.x*WGROWS;          // WG-wide row base

  // B-fragment direct load (shared by both M-tiles)
#define BFR(BASE, BLK) (*(const bf16x8*)(wpack + (BASE) + (((u32)(BLK)*64u + (u32)lane)*16u)))
  // A-fragment read from an h-buffer (r3-verified layout + swizzle); row = MTI*16+cl
#define AFRAG(REG, MTI, KK) (*(const bf16x8*)(smem + (REG) + \
    ((((u32)((MTI)*16 + cl))*512u + (u32)(KK)*64u + (u32)kg*16u) ^ (((u32)((MTI)*16 + cl) & 7u) << 4))))
  // pointwise h store offset; row = MTI*16+kg*4+r, unit col = JC*16+cl
#define HOFF(REG, ROW, JC) ((REG) + ((((u32)(ROW))*512u + (u32)((JC)*16+cl)*2u) ^ ((((u32)(ROW)) & 7u) << 4)))

  // persistent per-thread state: c packed bf16 mt-pairs (wave's own 4 jc) = 32 regs
  u32 c0p[4][4];   // [j][r] ; lo16 = mt0, hi16 = mt1
  u32 c1p[4][4];
#pragma unroll
  for (int j=0;j<4;++j)
#pragma unroll
    for (int r=0;r<4;++r){ c0p[j][r]=0u; c1p[j][r]=0u; }

  // zero H0[0] and H1[0] (read as "old" at t=0)
  {
    bf16x8 z = bzero8();
#pragma unroll
    for (int i = 0; i < 4; ++i){
      u32 off = ((u32)tid + (u32)i*NTHR)*16u;
      if (off < HBUF_SZ){
        *(bf16x8*)(smem + H0_OFF(0) + off) = z;
        *(bf16x8*)(smem + H1_OFF(0) + off) = z;
      }
    }
  }
  __syncthreads();

#pragma unroll 1
  for (int t = 0; t < STEPS; ++t){
    const u32 p   = (u32)(t & 1);
    const u32 H0o = H0_OFF(p),  H0n = H0_OFF(1u-p);
    const u32 H1o = H1_OFF(p),  H1n = H1_OFF(1u-p);

    // -------- augmented input fragments for both M-tiles (registers) --------
    bf16x8 augf[MT];
#pragma unroll
    for (int mt=0; mt<MT; ++mt) augf[mt] = bzero8();
    if (kg == 0){
#pragma unroll
      for (int mt=0; mt<MT; ++mt){
        u32 mg = (u32)m0w + mt*16 + cl, b = mg >> 9, n = mg & 511;
        float4 dt  = (t   < 96) ? ((const float4*)hist)[(u64)(b*96 + t)*512 + n]
                                : ((const float4*)fut )[(u64)(b*24 + (t-96))*512 + n];
        int t1 = t + 1;
        float4 dt1 = (t1  < 96) ? ((const float4*)hist)[(u64)(b*96 + t1)*512 + n]
                                : ((const float4*)fut )[(u64)(b*24 + (t1-96))*512 + n];
        bf16x8 a = bzero8();
        a[0] = (__bf16)dt.x; a[1] = (__bf16)dt1.y; a[2] = (__bf16)dt1.z; a[3] = (__bf16)dt1.w;
        a[4] = (__bf16)1.0f;
        augf[mt] = a;
      }
    }

    // ===================== LAYER 0 (wave handles jc = wid*4+j) =====================
#pragma unroll 1
    for (int j = 0; j < 4; ++j){
      const int jc = wid*4 + j;
      const u32 base = L0_OFF + (u32)jc*L0_STAGE_BYTES;
      f32x4 ac[MT][4];
#pragma unroll
      for (int mt=0; mt<MT; ++mt)
#pragma unroll
        for (int g=0; g<4; ++g) ac[mt][g] = (f32x4){0.f,0.f,0.f,0.f};
#pragma unroll
      for (int kk = 0; kk < 9; ++kk){
        bf16x8 a[MT];
#pragma unroll
        for (int mt=0; mt<MT; ++mt) a[mt] = (kk < 8) ? AFRAG(H0o, mt, kk) : augf[mt];
#pragma unroll
        for (int g = 0; g < 4; ++g){
          bf16x8 bfr = BFR(base, kk*4+g);
#pragma unroll
          for (int mt=0; mt<MT; ++mt) ac[mt][g] = mfma16(a[mt], bfr, ac[mt][g]);
        }
      }
#pragma unroll
      for (int r = 0; r < 4; ++r){
        u32 packed = c0p[j][r], newpack = 0u;
#pragma unroll
        for (int mt = 0; mt < MT; ++mt){
          float iv = sigm (ac[mt][0][r]);
          float fv = sigm (ac[mt][1][r]);
          float gv = tanh_(ac[mt][2][r]);
          float ov = sigm (ac[mt][3][r]);
          float cold = __uint_as_float((mt ? (packed >> 16) : (packed & 0xffffu)) << 16);
          float cn = fv*cold + iv*gv;
          newpack |= f2bf(cn) << (mt*16);
          float hn = ov*tanh_(cn);
          int row = mt*16 + kg*4 + r;
          *(uint16_t*)(smem + HOFF(H0n, row, jc)) = (uint16_t)f2bf(hn);
        }
        c0p[j][r] = newpack;
      }
    }
    __syncthreads();   // h0_new complete & visible

    // ===================== LAYER 1 =====================
#pragma unroll 1
    for (int j = 0; j < 4; ++j){
      const int jc = wid*4 + j;
      const u32 baseA = L1_OFF + (u32)jc*L1_JC_BYTES;
      const u32 baseB = baseA + L1A_STAGE_BYTES;
      f32x4 ac[MT][4];
#pragma unroll
      for (int mt=0; mt<MT; ++mt)
#pragma unroll
        for (int g=0; g<4; ++g) ac[mt][g] = (f32x4){0.f,0.f,0.f,0.f};
      // stage A: k = 0..255 (h0_new from LDS)
#pragma unroll
      for (int kk = 0; kk < 8; ++kk){
        bf16x8 a[MT];
#pragma unroll
        for (int mt=0; mt<MT; ++mt) a[mt] = AFRAG(H0n, mt, kk);
#pragma unroll
        for (int g = 0; g < 4; ++g){
          bf16x8 bfr = BFR(baseA, kk*4+g);
#pragma unroll
          for (int mt=0; mt<MT; ++mt) ac[mt][g] = mfma16(a[mt], bfr, ac[mt][g]);
        }
      }
      // stage B: k = 256..511 (h1_old from LDS) + aug/bias
#pragma unroll
      for (int kk = 0; kk < 9; ++kk){
        bf16x8 a[MT];
#pragma unroll
        for (int mt=0; mt<MT; ++mt) a[mt] = (kk < 8) ? AFRAG(H1o, mt, kk) : augf[mt];
#pragma unroll
        for (int g = 0; g < 4; ++g){
          bf16x8 bfr = BFR(baseB, kk*4+g);
#pragma unroll
          for (int mt=0; mt<MT; ++mt) ac[mt][g] = mfma16(a[mt], bfr, ac[mt][g]);
        }
      }
#pragma unroll
      for (int r = 0; r < 4; ++r){
        u32 packed = c1p[j][r], newpack = 0u;
#pragma unroll
        for (int mt = 0; mt < MT; ++mt){
          float iv = sigm (ac[mt][0][r]);
          float fv = sigm (ac[mt][1][r]);
          float gv = tanh_(ac[mt][2][r]);
          float ov = sigm (ac[mt][3][r]);
          float cold = __uint_as_float((mt ? (packed >> 16) : (packed & 0xffffu)) << 16);
          float cn = fv*cold + iv*gv;
          newpack |= f2bf(cn) << (mt*16);
          float hn = ov*tanh_(cn);
          int row = mt*16 + kg*4 + r;
          *(uint16_t*)(smem + HOFF(H1n, row, jc)) = (uint16_t)f2bf(hn);
        }
        c1p[j][r] = newpack;
      }
    }
    __syncthreads();   // h1_new complete & visible

    // ===================== HEAD (wave 0 only; A = relu(h1_new)) =====================
    if (wid == 0){
      f32x4 ha[MT];
#pragma unroll
      for (int mt=0; mt<MT; ++mt) ha[mt] = (f32x4){0.f,0.f,0.f,0.f};
#pragma unroll
      for (int kk = 0; kk < 9; ++kk){
        bf16x8 bfr = BFR(HEAD_OFF, kk);
#pragma unroll
        for (int mt=0; mt<MT; ++mt){
          bf16x8 a = (kk < 8) ? relu8(AFRAG(H1n, mt, kk)) : augf[mt];
          ha[mt] = mfma16(a, bfr, ha[mt]);
        }
      }
#pragma unroll
      for (int mt = 0; mt < MT; ++mt)
#pragma unroll
        for (int r = 0; r < 4; ++r){
          float a  = ha[mt][r];
          float sp = softplus_(a) + 1e-6f;
          float spn = __shfl_xor(sp, 1, 64);
          u32 mg = (u32)m0w + mt*16 + (u32)(kg*4 + r);
          u64 oidx = (u64)(mg >> 9)*(STEPS*512) + (u64)t*512 + (mg & 511);
          if (cl == 0){
            float e = eps[(u64)t*BN + mg];
            out[oidx]            = fmaf(spn, e, a);   // preds
            out[2ull*OSZ + oidx] = a;                 // mus
          } else if (cl == 1){
            out[3ull*OSZ + oidx] = sp;                // sigmas
          }
        }
    }
    // no barrier needed here: next-step L0 touches only H0 buffers; L1(t+1) writes to
    // H1o(t) are gated by the post-L0 barrier of t+1, after wave 0 finished head.
  }
#undef BFR
#undef AFRAG
#undef HOFF
}

// ---------------- launch ----------------
extern "C" void kernel_launch(void* const* d_in, const int* in_sizes, int n_in,
                              void* d_out, int out_size, void* d_ws, size_t ws_size,
                              hipStream_t stream)
{
  (void)in_sizes; (void)n_in; (void)out_size; (void)ws_size;
  const float* hist   = (const float*)d_in[0];
  const float* fut    = (const float*)d_in[1];
  const float* W_embed= (const float*)d_in[3];
  const float* b_embed= (const float*)d_in[4];
  const float* W_ih0  = (const float*)d_in[5];
  const float* W_hh0  = (const float*)d_in[6];
  const float* b_ih0  = (const float*)d_in[7];
  const float* b_hh0  = (const float*)d_in[8];
  const float* W_ih1  = (const float*)d_in[9];
  const float* W_hh1  = (const float*)d_in[10];
  const float* b_ih1  = (const float*)d_in[11];
  const float* b_hh1  = (const float*)d_in[12];
  const float* W_mu   = (const float*)d_in[13];
  const float* b_mu   = (const float*)d_in[14];
  const float* W_sig  = (const float*)d_in[15];
  const float* b_sig  = (const float*)d_in[16];
  uint8_t* ws  = (uint8_t*)d_ws;
  float*   out = (float*)d_out;

  hipLaunchKernelGGL(k_dots, dim3(4), dim3(256), 0, stream,
                     W_embed, b_embed, W_ih0, b_ih0, b_hh0, (float*)(ws + PREP_OFF));
  hipLaunchKernelGGL(k_pack, dim3(PACKED_BYTES/2/256), dim3(256), 0, stream,
                     W_ih0, W_hh0, W_ih1, W_hh1, W_mu, b_mu, W_sig, b_sig,
                     b_ih1, b_hh1, (const float*)(ws + PREP_OFF), ws);
  hipLaunchKernelGGL(k_eps, dim3((STEPS*BN)/256), dim3(256), 0, stream,
                     (float*)(ws + EPS_OFF));
  hipLaunchKernelGGL(k_reals, dim3((u32)((OSZ + 255)/256)), dim3(256), 0, stream,
                     hist, fut, out);
  hipLaunchKernelGGL(k_main, dim3(NWG), dim3(NTHR), 0, stream,
                     hist, fut, ws, (const float*)(ws + EPS_OFF), out);
}

// Round 18
// 8935.682 us; speedup vs baseline: 3.4263x; 1.0347x over previous
//
#include <hip/hip_runtime.h>
#include <hip/hip_bf16.h>
#include <stdint.h>

typedef uint32_t u32;
typedef uint64_t u64;
typedef __bf16  bf16x8 __attribute__((ext_vector_type(8)));
typedef float   f32x4  __attribute__((ext_vector_type(4)));

#define DEVI __device__ __forceinline__

// ---------------- problem constants ----------------
#define BB    64
#define NN    512
#define BN    32768            // B*N
#define STEPS 119
#define HD    256
#define OSZ   3899392ull       // 64*119*512

// ---------------- geometry: 4 waves/WG x 4 jc, WG owns 32 rows (2 M-tiles); 2 WGs/CU ----------------
#define NWAVE   4
#define MT      2
#define WGROWS  32
#define NWG     1024
#define NTHR    256

// ---------------- packed weight stream (bf16) ----------------
#define L0_STAGE_BYTES  36864
#define L1A_STAGE_BYTES 32768
#define L1B_STAGE_BYTES 36864
#define HEAD_STAGE_BYTES 9216
#define L0_OFF      0u
#define L1_OFF      (16u*L0_STAGE_BYTES)                 // 589824
#define L1_JC_BYTES (L1A_STAGE_BYTES + L1B_STAGE_BYTES)  // 69632
#define HEAD_OFF    (L1_OFF + 16u*L1_JC_BYTES)           // 1703936
#define PACKED_BYTES (HEAD_OFF + HEAD_STAGE_BYTES)       // 1713152

// ws layout (bytes)
#define PREP_OFF  1835008u                  // A[1024], bias0[1024] f32
#define EPS_OFF   4194304u                  // 119*32768 f32

// LDS: 4 WG-shared h buffers in A-FRAGMENT-STREAM layout:
//   h[mt][kk][lane][16B]  (mt<2, kk<8, lane<64) = 16KB per buffer.
//   Reads are lane-linear (conflict-free); writes are 2B scatter.
#define HBUF_SZ   16384u
#define H0_OFF(p) ((u32)(p)*HBUF_SZ)
#define H1_OFF(p) ((2u+(u32)(p))*HBUF_SZ)
#define SMEM_TOTAL (4u*HBUF_SZ)             // 65536 (64KB) -> 2 WGs/CU, 8 waves = 2/SIMD

// ---------------- math helpers ----------------
DEVI float exp2g(float x){ return __builtin_amdgcn_exp2f(x); }
DEVI float rcpg (float x){ return __builtin_amdgcn_rcpf(x); }
DEVI float log2g(float x){ return __builtin_amdgcn_logf(x); }
#define LOG2E 1.4426950408889634f
#define LN2   0.6931471805599453f
DEVI float sigm(float x){ return rcpg(1.0f + exp2g(-LOG2E*x)); }
DEVI float tanh_(float x){
  float ax = fabsf(x);
  float e  = exp2g(2.0f*LOG2E*ax);
  float r  = 1.0f - 2.0f*rcpg(e + 1.0f);
  return copysignf(r, x);
}
DEVI float softplus_(float x){
  float ax = fabsf(x);
  return fmaxf(x, 0.0f) + log2g(1.0f + exp2g(-LOG2E*ax)) * LN2;
}
DEVI u32 f2bf(float f){ u32 u = __float_as_uint(f); return (u + 0x7FFFu + ((u>>16)&1u)) >> 16; }
// native RNE cvt (1 VALU) for hot paths
DEVI u32 bfbits(float f){ __bf16 b = (__bf16)f; uint16_t u; __builtin_memcpy(&u, &b, 2); return (u32)u; }

DEVI f32x4 mfma16(bf16x8 a, bf16x8 b, f32x4 c){
  return __builtin_amdgcn_mfma_f32_16x16x32_bf16(a, b, c, 0, 0, 0);
}
DEVI bf16x8 bzero8(){ bf16x8 z;
#pragma unroll
  for (int i=0;i<8;++i) z[i] = (__bf16)0.0f;
  return z; }
DEVI bf16x8 relu8(bf16x8 v){ bf16x8 r;
#pragma unroll
  for (int i=0;i<8;++i){ float x = (float)v[i]; r[i] = x > 0.0f ? v[i] : (__bf16)0.0f; }
  return r; }

// ---------------- prep: A[] and folded bias for layer0 (verified r2) ----------------
__global__ void k_dots(const float* __restrict__ W_embed, const float* __restrict__ b_embed,
                       const float* __restrict__ W_ih0, const float* __restrict__ b_ih0,
                       const float* __restrict__ b_hh0, float* __restrict__ prep)
{
  int i = blockIdx.x*256 + threadIdx.x;
  if (i >= 1024) return;
  float a = 0.f, bb = 0.f;
  for (int e = 0; e < 64; ++e){
    float w = W_ih0[i*67 + e];
    a  += W_embed[e] * w;
    bb += b_embed[e] * w;
  }
  prep[i]        = a;
  prep[1024 + i] = bb + b_ih0[i] + b_hh0[i];
}

// ---------------- prep: pack all weights into stream order (bf16, verified r3) ----------------
__global__ void k_pack(const float* __restrict__ W_ih0, const float* __restrict__ W_hh0,
                       const float* __restrict__ W_ih1, const float* __restrict__ W_hh1,
                       const float* __restrict__ W_mu,  const float* __restrict__ b_mu,
                       const float* __restrict__ W_sig, const float* __restrict__ b_sig,
                       const float* __restrict__ b_ih1, const float* __restrict__ b_hh1,
                       const float* __restrict__ prep, uint8_t* __restrict__ ws)
{
  u32 e = blockIdx.x*256 + threadIdx.x;
  if (e >= PACKED_BYTES/2) return;
  u32 byte = e*2;
  float v = 0.0f;
  if (byte < L1_OFF){
    u32 jc  = byte / L0_STAGE_BYTES;
    u32 rr  = byte % L0_STAGE_BYTES;
    u32 f16i = rr >> 4;  u32 j = (rr & 15) >> 1;
    u32 lane = f16i & 63; u32 kkg = f16i >> 6;
    u32 kk = kkg >> 2, g = kkg & 3;
    u32 row = g*256 + jc*16 + (lane & 15);
    u32 k   = kk*32 + (lane>>4)*8 + j;
    if (k < 256) v = W_hh0[row*256 + k];
    else { u32 ka = k - 256;
      v = (ka==0) ? prep[row]
        : (ka<=3) ? W_ih0[row*67 + 64 + (ka-1)]
        : (ka==4) ? prep[1024 + row] : 0.0f; }
  } else if (byte < HEAD_OFF){
    u32 rel = byte - L1_OFF;
    u32 jc  = rel / L1_JC_BYTES;
    u32 r2  = rel % L1_JC_BYTES;
    u32 kh  = (r2 >= L1A_STAGE_BYTES) ? 1u : 0u;
    u32 r3  = r2 - kh*L1A_STAGE_BYTES;
    u32 f16i = r3 >> 4;  u32 j = (r3 & 15) >> 1;
    u32 lane = f16i & 63; u32 kkg = f16i >> 6;
    u32 kk = (kkg >> 2) + kh*8; u32 g = kkg & 3;
    u32 row = g*256 + jc*16 + (lane & 15);
    u32 k   = kk*32 + (lane>>4)*8 + j;
    if (k < 256)       v = W_ih1[row*256 + k];
    else if (k < 512)  v = W_hh1[row*256 + (k-256)];
    else { u32 ka = k - 512; v = (ka==4) ? (b_ih1[row] + b_hh1[row]) : 0.0f; }
  } else {
    u32 rel = byte - HEAD_OFF;
    u32 f16i = rel >> 4; u32 j = (rel & 15) >> 1;
    u32 lane = f16i & 63; u32 kk = f16i >> 6;
    u32 hrow = lane & 15;
    u32 k = kk*32 + (lane>>4)*8 + j;
    if (hrow == 0)      v = (k < 256) ? W_mu[k]  : (k==260 ? b_mu[0]  : 0.0f);
    else if (hrow == 1) v = (k < 256) ? W_sig[k] : (k==260 ? b_sig[0] : 0.0f);
    else v = 0.0f;
  }
  ((uint16_t*)ws)[e] = (uint16_t)f2bf(v);
}

// ---------------- eps (VERIFIED round 2): partitionable threefry, out = x0^x1 ----------------
DEVI float erfinv_f(float x){
  float w = -log1pf(-x*x);
  float p;
  if (w < 5.0f){
    w = w - 2.5f;
    p = 2.81022636e-08f;
    p = fmaf(p, w, 3.43273939e-07f);
    p = fmaf(p, w, -3.5233877e-06f);
    p = fmaf(p, w, -4.39150654e-06f);
    p = fmaf(p, w, 0.00021858087f);
    p = fmaf(p, w, -0.00125372503f);
    p = fmaf(p, w, -0.00417768164f);
    p = fmaf(p, w, 0.246640727f);
    p = fmaf(p, w, 1.50140941f);
  } else {
    w = sqrtf(w) - 3.0f;
    p = -0.000200214257f;
    p = fmaf(p, w, 0.000100950558f);
    p = fmaf(p, w, 0.00134934322f);
    p = fmaf(p, w, -0.00367342844f);
    p = fmaf(p, w, 0.00573950773f);
    p = fmaf(p, w, -0.0076224613f);
    p = fmaf(p, w, 0.00943887047f);
    p = fmaf(p, w, 1.00167406f);
    p = fmaf(p, w, 2.83297682f);
  }
  return p*x;
}
__global__ void k_eps(float* __restrict__ epsbuf){
  u32 i = blockIdx.x*256u + threadIdx.x;
  if (i >= (u32)(STEPS*BN)) return;
  const u32 ks0 = 0u, ks1 = 42u, ks2 = 0x1BD11BF0u;  // 0x1BD11BDA ^ 0 ^ 42
  u32 x0 = 0u + ks0, x1 = i + ks1;
#define TFR(r) { x0 += x1; x1 = (x1<<r)|(x1>>(32-r)); x1 ^= x0; }
  TFR(13) TFR(15) TFR(26) TFR(6)   x0 += ks1; x1 += ks2 + 1u;
  TFR(17) TFR(29) TFR(16) TFR(24)  x0 += ks2; x1 += ks0 + 2u;
  TFR(13) TFR(15) TFR(26) TFR(6)   x0 += ks0; x1 += ks1 + 3u;
  TFR(17) TFR(29) TFR(16) TFR(24)  x0 += ks1; x1 += ks2 + 4u;
  TFR(13) TFR(15) TFR(26) TFR(6)   x0 += ks2; x1 += ks0 + 5u;
#undef TFR
  u32 bits = x0 ^ x1;
  float f = __uint_as_float((bits >> 9) | 0x3F800000u) - 1.0f;
  const float lo = -0.99999994f;
  float u = fmaf(f, 2.0f, lo);
  u = fmaxf(u, lo);
  epsbuf[i] = 1.41421354f * erfinv_f(u);
}

// ---------------- reals output (verified r2) ----------------
__global__ void k_reals(const float* __restrict__ hist, const float* __restrict__ fut,
                        float* __restrict__ out)
{
  u32 i = blockIdx.x*256 + threadIdx.x;
  if (i >= (u32)OSZ) return;
  u32 n = i & 511; u32 rest = i >> 9;
  u32 t = rest % STEPS; u32 b = rest / STEPS;
  u32 tt = t + 1;
  float v = (tt < 96) ? hist[(((u64)b*96 + tt)*512 + n)*4]
                      : fut [(((u64)b*24 + (tt-96))*512 + n)*4];
  out[OSZ + i] = v;
}

// ---------------- main: N-split waves, frag-layout h, direct-from-L2 weights, 2 WGs/CU ----------------
__global__ __launch_bounds__(NTHR, 1) void k_main(
    const float* __restrict__ hist, const float* __restrict__ fut,
    const uint8_t* __restrict__ wpack, const float* __restrict__ eps,
    float* __restrict__ out)
{
  __shared__ uint8_t smem[SMEM_TOTAL];
  const int tid = threadIdx.x, lane = tid & 63, wid = tid >> 6;
  const int cl = lane & 15, kg = lane >> 4;
  const int m0w = blockIdx.x*WGROWS;          // WG-wide row base

  // B-fragment direct load (shared by both M-tiles)
#define BFR(BASE, BLK) (*(const bf16x8*)(wpack + (BASE) + (((u32)(BLK)*64u + (u32)lane)*16u)))
  // A-fragment read: frag-stream layout, lane-linear => conflict-free, imm-offset addressing
#define AFRAG(REG, MTI, KK) (*(const bf16x8*)(smem + (REG) + \
    ((((u32)(MTI)*8u + (u32)(KK))*64u + (u32)lane)*16u)))

  // h scatter-write address pieces:
  //   haddr = REG + mt*8192 + jc*512 + partcl + (kg*4+r)*16 ; partcl = (cl>>3)*256 + (cl&7)*2
  const u32 partcl = ((u32)(cl>>3))*256u + ((u32)(cl&7))*2u;
  const u32 kg16 = (u32)kg*64u;   // (kg*4)*16

  // persistent per-thread state: c packed bf16 mt-pairs (wave's own 4 jc) = 32 regs
  u32 c0p[4][4];   // [j][r] ; lo16 = mt0, hi16 = mt1
  u32 c1p[4][4];
#pragma unroll
  for (int j=0;j<4;++j)
#pragma unroll
    for (int r=0;r<4;++r){ c0p[j][r]=0u; c1p[j][r]=0u; }

  // zero H0[0] and H1[0] (read as "old" at t=0)
  {
    bf16x8 z = bzero8();
#pragma unroll
    for (int i = 0; i < 4; ++i){
      u32 off = ((u32)tid + (u32)i*NTHR)*16u;
      if (off < HBUF_SZ){
        *(bf16x8*)(smem + H0_OFF(0) + off) = z;
        *(bf16x8*)(smem + H1_OFF(0) + off) = z;
      }
    }
  }
  __syncthreads();

#pragma unroll 1
  for (int t = 0; t < STEPS; ++t){
    const u32 p   = (u32)(t & 1);
    const u32 H0o = H0_OFF(p),  H0n = H0_OFF(1u-p);
    const u32 H1o = H1_OFF(p),  H1n = H1_OFF(1u-p);

    // -------- augmented input fragments for both M-tiles (registers) --------
    bf16x8 augf[MT];
#pragma unroll
    for (int mt=0; mt<MT; ++mt) augf[mt] = bzero8();
    if (kg == 0){
#pragma unroll
      for (int mt=0; mt<MT; ++mt){
        u32 mg = (u32)m0w + mt*16 + cl, b = mg >> 9, n = mg & 511;
        float4 dt  = (t   < 96) ? ((const float4*)hist)[(u64)(b*96 + t)*512 + n]
                                : ((const float4*)fut )[(u64)(b*24 + (t-96))*512 + n];
        int t1 = t + 1;
        float4 dt1 = (t1  < 96) ? ((const float4*)hist)[(u64)(b*96 + t1)*512 + n]
                                : ((const float4*)fut )[(u64)(b*24 + (t1-96))*512 + n];
        bf16x8 a = bzero8();
        a[0] = (__bf16)dt.x; a[1] = (__bf16)dt1.y; a[2] = (__bf16)dt1.z; a[3] = (__bf16)dt1.w;
        a[4] = (__bf16)1.0f;
        augf[mt] = a;
      }
    }

    // ===================== LAYER 0 (wave handles jc = wid*4+j) =====================
#pragma unroll 1
    for (int j = 0; j < 4; ++j){
      const int jc = wid*4 + j;
      const u32 base = L0_OFF + (u32)jc*L0_STAGE_BYTES;
      const u32 wja = (u32)jc*512u + partcl + kg16;   // jc-dependent write base piece
      f32x4 ac[MT][4];
#pragma unroll
      for (int mt=0; mt<MT; ++mt)
#pragma unroll
        for (int g=0; g<4; ++g) ac[mt][g] = (f32x4){0.f,0.f,0.f,0.f};
#pragma unroll
      for (int kk = 0; kk < 9; ++kk){
        bf16x8 a[MT];
#pragma unroll
        for (int mt=0; mt<MT; ++mt) a[mt] = (kk < 8) ? AFRAG(H0o, mt, kk) : augf[mt];
#pragma unroll
        for (int g = 0; g < 4; ++g){
          bf16x8 bfr = BFR(base, kk*4+g);
#pragma unroll
          for (int mt=0; mt<MT; ++mt) ac[mt][g] = mfma16(a[mt], bfr, ac[mt][g]);
        }
      }
#pragma unroll
      for (int r = 0; r < 4; ++r){
        u32 packed = c0p[j][r], newpack = 0u;
#pragma unroll
        for (int mt = 0; mt < MT; ++mt){
          float iv = sigm (ac[mt][0][r]);
          float fv = sigm (ac[mt][1][r]);
          float gv = tanh_(ac[mt][2][r]);
          float ov = sigm (ac[mt][3][r]);
          float cold = __uint_as_float((mt ? (packed >> 16) : (packed & 0xffffu)) << 16);
          float cn = fv*cold + iv*gv;
          newpack |= bfbits(cn) << (mt*16);
          float hn = ov*tanh_(cn);
          *(uint16_t*)(smem + H0n + (u32)mt*8192u + wja + (u32)r*16u) = (uint16_t)bfbits(hn);
        }
        c0p[j][r] = newpack;
      }
    }
    __syncthreads();   // h0_new complete & visible

    // ===================== LAYER 1 =====================
#pragma unroll 1
    for (int j = 0; j < 4; ++j){
      const int jc = wid*4 + j;
      const u32 baseA = L1_OFF + (u32)jc*L1_JC_BYTES;
      const u32 baseB = baseA + L1A_STAGE_BYTES;
      const u32 wja = (u32)jc*512u + partcl + kg16;
      f32x4 ac[MT][4];
#pragma unroll
      for (int mt=0; mt<MT; ++mt)
#pragma unroll
        for (int g=0; g<4; ++g) ac[mt][g] = (f32x4){0.f,0.f,0.f,0.f};
      // stage A: k = 0..255 (h0_new from LDS)
#pragma unroll
      for (int kk = 0; kk < 8; ++kk){
        bf16x8 a[MT];
#pragma unroll
        for (int mt=0; mt<MT; ++mt) a[mt] = AFRAG(H0n, mt, kk);
#pragma unroll
        for (int g = 0; g < 4; ++g){
          bf16x8 bfr = BFR(baseA, kk*4+g);
#pragma unroll
          for (int mt=0; mt<MT; ++mt) ac[mt][g] = mfma16(a[mt], bfr, ac[mt][g]);
        }
      }
      // stage B: k = 256..511 (h1_old from LDS) + aug/bias
#pragma unroll
      for (int kk = 0; kk < 9; ++kk){
        bf16x8 a[MT];
#pragma unroll
        for (int mt=0; mt<MT; ++mt) a[mt] = (kk < 8) ? AFRAG(H1o, mt, kk) : augf[mt];
#pragma unroll
        for (int g = 0; g < 4; ++g){
          bf16x8 bfr = BFR(baseB, kk*4+g);
#pragma unroll
          for (int mt=0; mt<MT; ++mt) ac[mt][g] = mfma16(a[mt], bfr, ac[mt][g]);
        }
      }
#pragma unroll
      for (int r = 0; r < 4; ++r){
        u32 packed = c1p[j][r], newpack = 0u;
#pragma unroll
        for (int mt = 0; mt < MT; ++mt){
          float iv = sigm (ac[mt][0][r]);
          float fv = sigm (ac[mt][1][r]);
          float gv = tanh_(ac[mt][2][r]);
          float ov = sigm (ac[mt][3][r]);
          float cold = __uint_as_float((mt ? (packed >> 16) : (packed & 0xffffu)) << 16);
          float cn = fv*cold + iv*gv;
          newpack |= bfbits(cn) << (mt*16);
          float hn = ov*tanh_(cn);
          *(uint16_t*)(smem + H1n + (u32)mt*8192u + wja + (u32)r*16u) = (uint16_t)bfbits(hn);
        }
        c1p[j][r] = newpack;
      }
    }
    __syncthreads();   // h1_new complete & visible

    // ===================== HEAD (wave 0 only; A = relu(h1_new)) =====================
    if (wid == 0){
      f32x4 ha[MT];
#pragma unroll
      for (int mt=0; mt<MT; ++mt) ha[mt] = (f32x4){0.f,0.f,0.f,0.f};
#pragma unroll
      for (int kk = 0; kk < 9; ++kk){
        bf16x8 bfr = BFR(HEAD_OFF, kk);
#pragma unroll
        for (int mt=0; mt<MT; ++mt){
          bf16x8 a = (kk < 8) ? relu8(AFRAG(H1n, mt, kk)) : augf[mt];
          ha[mt] = mfma16(a, bfr, ha[mt]);
        }
      }
#pragma unroll
      for (int mt = 0; mt < MT; ++mt)
#pragma unroll
        for (int r = 0; r < 4; ++r){
          float a  = ha[mt][r];
          float sp = softplus_(a) + 1e-6f;
          float spn = __shfl_xor(sp, 1, 64);
          u32 mg = (u32)m0w + mt*16 + (u32)(kg*4 + r);
          u64 oidx = (u64)(mg >> 9)*(STEPS*512) + (u64)t*512 + (mg & 511);
          if (cl == 0){
            float e = eps[(u64)t*BN + mg];
            out[oidx]            = fmaf(spn, e, a);   // preds
            out[2ull*OSZ + oidx] = a;                 // mus
          } else if (cl == 1){
            out[3ull*OSZ + oidx] = sp;                // sigmas
          }
        }
    }
    // no barrier needed here: next-step L0 touches only H0 buffers; L1(t+1) writes to
    // H1o(t) are gated by the post-L0 barrier of t+1, after wave 0 finished head.
  }
#undef BFR
#undef AFRAG
}

// ---------------- launch ----------------
extern "C" void kernel_launch(void* const* d_in, const int* in_sizes, int n_in,
                              void* d_out, int out_size, void* d_ws, size_t ws_size,
                              hipStream_t stream)
{
  (void)in_sizes; (void)n_in; (void)out_size; (void)ws_size;
  const float* hist   = (const float*)d_in[0];
  const float* fut    = (const float*)d_in[1];
  const float* W_embed= (const float*)d_in[3];
  const float* b_embed= (const float*)d_in[4];
  const float* W_ih0  = (const float*)d_in[5];
  const float* W_hh0  = (const float*)d_in[6];
  const float* b_ih0  = (const float*)d_in[7];
  const float* b_hh0  = (const float*)d_in[8];
  const float* W_ih1  = (const float*)d_in[9];
  const float* W_hh1  = (const float*)d_in[10];
  const float* b_ih1  = (const float*)d_in[11];
  const float* b_hh1  = (const float*)d_in[12];
  const float* W_mu   = (const float*)d_in[13];
  const float* b_mu   = (const float*)d_in[14];
  const float* W_sig  = (const float*)d_in[15];
  const float* b_sig  = (const float*)d_in[16];
  uint8_t* ws  = (uint8_t*)d_ws;
  float*   out = (float*)d_out;

  hipLaunchKernelGGL(k_dots, dim3(4), dim3(256), 0, stream,
                     W_embed, b_embed, W_ih0, b_ih0, b_hh0, (float*)(ws + PREP_OFF));
  hipLaunchKernelGGL(k_pack, dim3(PACKED_BYTES/2/256), dim3(256), 0, stream,
                     W_ih0, W_hh0, W_ih1, W_hh1, W_mu, b_mu, W_sig, b_sig,
                     b_ih1, b_hh1, (const float*)(ws + PREP_OFF), ws);
  hipLaunchKernelGGL(k_eps, dim3((STEPS*BN)/256), dim3(256), 0, stream,
                     (float*)(ws + EPS_OFF));
  hipLaunchKernelGGL(k_reals, dim3((u32)((OSZ + 255)/256)), dim3(256), 0, stream,
                     hist, fut, out);
  hipLaunchKernelGGL(k_main, dim3(NWG), dim3(NTHR), 0, stream,
                     hist, fut, ws, (const float*)(ws + EPS_OFF), out);
}